// Round 17
// baseline (1720.733 us; speedup 1.0000x reference)
//
#include <hip/hip_runtime.h>
#include <math.h>

#define TT 1024
#define DD 128
#define UU 64

__device__ __forceinline__ float sigm(float x) {
    return __builtin_amdgcn_rcpf(1.0f + __expf(-x));
}
__device__ __forceinline__ float tanhfast(float x) {
    float e = __expf(2.0f * x);
    return fmaf(-2.0f, __builtin_amdgcn_rcpf(e + 1.0f), 1.0f);
}

// DPP-based full-wave (64-lane) sum, result broadcast via readlane(63).
template<int CTRL>
__device__ __forceinline__ float dpp_add(float v) {
    return v + __int_as_float(__builtin_amdgcn_update_dpp(
        0, __float_as_int(v), CTRL, 0xf, 0xf, true));
}
__device__ __forceinline__ float wave_red_sum(float v) {
    v = dpp_add<0x111>(v);   // row_shr:1
    v = dpp_add<0x112>(v);   // row_shr:2
    v = dpp_add<0x114>(v);   // row_shr:4
    v = dpp_add<0x118>(v);   // row_shr:8
    v = dpp_add<0x142>(v);   // row_bcast:15
    v = dpp_add<0x143>(v);   // row_bcast:31
    return __int_as_float(__builtin_amdgcn_readlane(__float_as_int(v), 63));
}

// broadcast h[k] from lane k (constant lane index after unroll)
#define RLF(H,K) __int_as_float(__builtin_amdgcn_readlane(__float_as_int(H), K))

// dot: per-lane h (lane k holds h[k], readlane broadcast on VALU) x f32
// weights from LDS float4 planes (stride 256*16B; consecutive lanes read
// consecutive 16B slots -> conflict-free ds_read_b128). 16 LDS insts + 128
// VALU ops per dot; zero L2 weight traffic.
#define DOTLW(res, HV, WFP) do {                                   \
    float a0 = 0.f, a1 = 0.f, a2 = 0.f, a3 = 0.f;                  \
    _Pragma("unroll")                                              \
    for (int _j = 0; _j < 16; ++_j) {                              \
        float4 wq = (WFP)[_j * 256];                               \
        a0 = fmaf(RLF(HV, 4*_j+0), wq.x, a0);                      \
        a1 = fmaf(RLF(HV, 4*_j+1), wq.y, a1);                      \
        a2 = fmaf(RLF(HV, 4*_j+2), wq.z, a2);                      \
        a3 = fmaf(RLF(HV, 4*_j+3), wq.w, a3);                      \
    }                                                              \
    res = (a0 + a1) + (a2 + a3);                                   \
} while (0)

// G1 dot: readlane-h x L2-streamed weights (coalesced across lanes; this is
// the one group whose weights stay on the L2 pipe by design).
#define DOTGW(res, HV, GP) do {                                    \
    float a0 = 0.f, a1 = 0.f, a2 = 0.f, a3 = 0.f;                  \
    _Pragma("unroll")                                              \
    for (int _j = 0; _j < 16; ++_j) {                              \
        a0 = fmaf(RLF(HV, 4*_j+0), (GP)[(4*_j+0) * 256], a0);      \
        a1 = fmaf(RLF(HV, 4*_j+1), (GP)[(4*_j+1) * 256], a1);      \
        a2 = fmaf(RLF(HV, 4*_j+2), (GP)[(4*_j+2) * 256], a2);      \
        a3 = fmaf(RLF(HV, 4*_j+3), (GP)[(4*_j+3) * 256], a3);      \
    }                                                              \
    res = (a0 + a1) + (a2 + a3);                                   \
} while (0)

// ================= x-part GEMM (round-4 proven version, f32) =================
__global__ __launch_bounds__(256, 1)
void xgemm(const float* __restrict__ obss, const float* __restrict__ W1,
           float* __restrict__ z1x, int t0, int chsh)
{
    const int tid = threadIdx.x;
    const int CH = 1 << chsh;
    __shared__ __align__(16) float xs[64 * DD];

    const int rbase = blockIdx.x * 64;
    for (int i = tid; i < 64 * (DD / 4); i += 256) {
        int rr = i >> 5;
        int k4 = i & 31;
        int r  = rbase + rr;
        int b  = r >> chsh;
        int tl = r & (CH - 1);
        ((float4*)xs)[rr * 32 + k4] =
            ((const float4*)(obss + ((size_t)b * TT + t0 + tl) * DD))[k4];
    }

    float w[DD];
    #pragma unroll
    for (int k = 0; k < DD; ++k) w[k] = W1[k * 256 + tid];
    __syncthreads();

    for (int rr = 0; rr < 64; rr += 2) {
        float a0=0,a1=0,a2=0,a3=0, b0=0,b1=0,b2=0,b3=0;
        const float4* x0 = (const float4*)(xs + rr * DD);
        const float4* x1 = (const float4*)(xs + (rr + 1) * DD);
        #pragma unroll
        for (int k4 = 0; k4 < DD / 4; ++k4) {
            float4 xv = x0[k4], yv = x1[k4];
            a0 = fmaf(xv.x, w[4*k4+0], a0);
            a1 = fmaf(xv.y, w[4*k4+1], a1);
            a2 = fmaf(xv.z, w[4*k4+2], a2);
            a3 = fmaf(xv.w, w[4*k4+3], a3);
            b0 = fmaf(yv.x, w[4*k4+0], b0);
            b1 = fmaf(yv.y, w[4*k4+1], b1);
            b2 = fmaf(yv.z, w[4*k4+2], b2);
            b3 = fmaf(yv.w, w[4*k4+3], b3);
        }
        size_t r = (size_t)rbase + rr;
        z1x[r * 256 + tid]       = (a0 + a1) + (a2 + a3);
        z1x[(r + 1) * 256 + tid] = (b0 + b1) + (b2 + b3);
    }
}

// ============ recurrent kernel: 3-group pipeline, 768 threads ================
// Pipe-balanced split (R16 post-mortem): W1h + W2h as f32 float4-planes in
// LDS (128 KB, 16 ds_read_b128/dot); W2x stays on L2 (G1, coalesced); h is
// broadcast on the VALU via readlane from each wave's own redundantly
// computed per-lane cell state. LDS ~1700cy, L2 ~1200cy, VALU ~1200cy/step.
__global__ __launch_bounds__(768) __attribute__((amdgpu_waves_per_eu(3, 3)))
void lstm_rec(const float* __restrict__ z1x,
              const float* __restrict__ W1, const float* __restrict__ W2,
              const float* __restrict__ gamma1, const float* __restrict__ beta1,
              const float* __restrict__ gc1, const float* __restrict__ bc1,
              const float* __restrict__ gamma2, const float* __restrict__ beta2,
              const float* __restrict__ gc2, const float* __restrict__ bc2,
              const float* __restrict__ Wd, const float* __restrict__ bd,
              float* __restrict__ out, float* __restrict__ state,
              int t0, int nsteps)
{
    const int tid  = threadIdx.x;
    const int b    = blockIdx.x;
    const int gid  = tid >> 8;        // 0, 1, 2
    const int stid = tid & 255;
    const int lane = stid & 63;
    const int wav  = stid >> 6;

    __shared__ __align__(16) float zsA[256], zsB[256], z2xs[256];
    __shared__ __align__(16) float h1ring[2][UU];
    __shared__ __align__(16) float h2hist[32 * 65];
    __shared__ __align__(16) float wds[UU * 16];
    __shared__ float bds[16];
    // f32 weight planes: wf4[m*4096 + j*256 + col] = W rows 4j..4j+3, col.
    // m=0: W1h (W1 rows 128..191), m=1: W2h (W2 rows 64..127). 128 KB.
    __shared__ __align__(16) float4 wf4[2 * 16 * 256];

    float* st = state + (size_t)b * 256;
    const int NS = nsteps;

    // ---- one-time staging: f32 global -> f32 LDS planes ----
    for (int i = tid; i < 2 * 16 * 256; i += 768) {
        int m   = i >> 12;
        int r   = i & 4095;
        int j   = r >> 8;
        int col = r & 255;
        const float* src = (m == 0) ? &W1[(DD + 4 * j) * 256 + col]
                                    : &W2[(UU + 4 * j) * 256 + col];
        wf4[i] = make_float4(src[0], src[256], src[512], src[768]);
    }

    if (gid == 0) {
        // ============================ G0: LAYER 1 ===========================
        const float4* wfp = &wf4[stid];            // W1h planes
        const float g1 = gamma1[stid], bb1 = beta1[stid];
        const float gcl = gc1[lane],  bcl = bc1[lane];

        float c1, h1v;
        if (t0 == 0) { c1 = 0.f; h1v = 0.f; }
        else         { c1 = st[lane]; h1v = st[64 + lane]; }

        const float* zrow = z1x + (size_t)b * NS * 256;
        float zx = zrow[stid];
        __syncthreads();                       // init (covers weight staging)

        #pragma unroll 1
        for (int n = 0; n <= NS + 2; ++n) {
            float zxn = zx;
            if (n < NS) {
                int tnl = (n + 1 < NS) ? n + 1 : n;
                zxn = zrow[(size_t)tnl * 256 + stid];

                float zdot;
                DOTLW(zdot, h1v, wfp);
                float z = zx + zdot;
                float s = wave_red_sum(z);
                float q = wave_red_sum(z * z);
                float mu  = s * (1.f/64.f);
                float var = q * (1.f/64.f) - mu * mu;
                float zn  = (z - mu) * __builtin_amdgcn_rsqf(var + 1e-12f) * g1 + bb1;
                zsA[stid] = (wav == 1) ? tanhfast(zn)
                          : (wav == 2) ? sigm(zn + 1.f)
                          :              sigm(zn);
            }
            __syncthreads();                   // B1
            if (n < NS) {
                float ai = zsA[lane],       aj = zsA[64 + lane];
                float af = zsA[128 + lane], ao = zsA[192 + lane];
                c1 = c1 * af + ai * aj;
                float cs = wave_red_sum(c1);
                float cq = wave_red_sum(c1 * c1);
                float cmu  = cs * (1.f/64.f);
                float cvar = cq * (1.f/64.f) - cmu * cmu;
                float cn   = (c1 - cmu) * __builtin_amdgcn_rsqf(cvar + 1e-12f) * gcl + bcl;
                h1v = tanhfast(cn) * ao;       // every wave holds h1 per-lane
                if (wav == 0) h1ring[n & 1][lane] = h1v;
            }
            __syncthreads();                   // B2
            zx = zxn;
        }
        if (t0 + NS < TT && wav == 0) {
            st[lane]      = c1;
            st[64 + lane] = h1v;
        }
    } else if (gid == 1) {
        // ================= G1: z2x feed + output projection =================
        const float* gp = W2 + stid;               // W2x rows 0..63, L2 path
        for (int i = stid; i < UU * 16; i += 256) wds[i] = Wd[i];
        if (stid < 16) bds[stid] = bd[stid];
        __syncthreads();                       // init

        #pragma unroll 1
        for (int n = 0; n <= NS + 2; ++n) {
            if (n >= 1 && n <= NS) {
                float h1l = h1ring[(n - 1) & 1][lane];  // per-lane h1
                float zxdot;
                DOTGW(zxdot, h1l, gp);
                z2xs[stid] = zxdot;
            }
            __syncthreads();                   // B1
            if ((n & 15) == 2 && n >= 18) {
                int rloc = stid >> 4;
                int a    = stid & 15;
                int m    = n - 18 + rloc;          // row within chunk
                float o = bds[a];
                const float* hrow = &h2hist[(m & 31) * 65];
                #pragma unroll
                for (int k = 0; k < UU; ++k)
                    o = fmaf(hrow[k], wds[k * 16 + a], o);
                out[((size_t)b * TT + (t0 + m)) * 16 + a] = tanhfast(o);
            }
            __syncthreads();                   // B2
        }
    } else {
        // ============================ G2: LAYER 2 ===========================
        const float4* wfp = &wf4[4096 + stid];     // W2h planes
        const float g2 = gamma2[stid], bb2 = beta2[stid];
        const float gcl = gc2[lane],  bcl = bc2[lane];

        float c2, h2v;
        if (t0 == 0) { c2 = 0.f; h2v = 0.f; }
        else         { c2 = st[128 + lane]; h2v = st[192 + lane]; }
        __syncthreads();                       // init (weights now visible)
        // z2h carried in-register; recomputed at chunk start AFTER the barrier
        float z2h = 0.f;
        if (t0 != 0) { DOTLW(z2h, h2v, wfp); }

        #pragma unroll 1
        for (int n = 0; n <= NS + 2; ++n) {
            if (n >= 2 && n <= NS + 1) {
                // cell2 for step n-2 (zsB written p2(n-1), crosses B2)
                float ai = zsB[lane],       aj = zsB[64 + lane];
                float af = zsB[128 + lane], ao = zsB[192 + lane];
                c2 = c2 * af + ai * aj;
                float cs = wave_red_sum(c2);
                float cq = wave_red_sum(c2 * c2);
                float cmu  = cs * (1.f/64.f);
                float cvar = cq * (1.f/64.f) - cmu * cmu;
                float cn   = (c2 - cmu) * __builtin_amdgcn_rsqf(cvar + 1e-12f) * gcl + bcl;
                h2v = tanhfast(cn) * ao;       // every wave holds h2 per-lane
                if (wav == 0) h2hist[((n - 2) & 31) * 65 + lane] = h2v;
                DOTLW(z2h, h2v, wfp);          // z2h for step n-1
            }
            __syncthreads();                   // B1
            if (n >= 1 && n <= NS) {
                float z2 = z2xs[stid] + z2h;
                float s2 = wave_red_sum(z2);
                float q2 = wave_red_sum(z2 * z2);
                float mu2  = s2 * (1.f/64.f);
                float var2 = q2 * (1.f/64.f) - mu2 * mu2;
                float zn2  = (z2 - mu2) * __builtin_amdgcn_rsqf(var2 + 1e-12f) * g2 + bb2;
                zsB[stid] = (wav == 1) ? tanhfast(zn2)
                          : (wav == 2) ? sigm(zn2 + 1.f)
                          :              sigm(zn2);
            }
            __syncthreads();                   // B2
        }
        if (t0 + NS < TT && wav == 0) {
            st[128 + lane] = c2;
            st[192 + lane] = h2v;
        }
    }
}

extern "C" void kernel_launch(void* const* d_in, const int* in_sizes, int n_in,
                              void* d_out, int out_size, void* d_ws, size_t ws_size,
                              hipStream_t stream) {
    (void)in_sizes; (void)n_in; (void)out_size;
    const float* obss   = (const float*)d_in[0];
    const float* W1     = (const float*)d_in[1];
    const float* gamma1 = (const float*)d_in[2];
    const float* beta1  = (const float*)d_in[3];
    const float* gc1    = (const float*)d_in[4];
    const float* bc1    = (const float*)d_in[5];
    const float* W2     = (const float*)d_in[6];
    const float* gamma2 = (const float*)d_in[7];
    const float* beta2  = (const float*)d_in[8];
    const float* gc2    = (const float*)d_in[9];
    const float* bc2    = (const float*)d_in[10];
    const float* Wd     = (const float*)d_in[11];
    const float* bd     = (const float*)d_in[12];
    float* out = (float*)d_out;

    float* state = (float*)d_ws;
    float* z1x   = (float*)((char*)d_ws + (size_t)256 * 256 * sizeof(float));

    int CH = 16;
    for (int c = TT; c >= 16; c >>= 1) {
        size_t need = (size_t)256 * c * 256 * sizeof(float)
                    + (size_t)256 * 256 * sizeof(float);
        if (need <= ws_size) { CH = c; break; }
    }
    int chsh = 31 - __builtin_clz((unsigned)CH);

    for (int t0 = 0; t0 < TT; t0 += CH) {
        xgemm<<<(256 * CH) / 64, 256, 0, stream>>>(obss, W1, z1x, t0, chsh);
        lstm_rec<<<256, 768, 0, stream>>>(z1x, W1, W2,
                                          gamma1, beta1, gc1, bc1,
                                          gamma2, beta2, gc2, bc2,
                                          Wd, bd, out, state, t0, CH);
    }
}